// Round 7
// baseline (34.125 us; speedup 1.0000x reference)
//
#include <hip/hip_runtime.h>
#include <math.h>

#define HID 512
#define EMB 1024
#define N1 1536
#define N2 256
#define P2S (128 * 256)

typedef __attribute__((ext_vector_type(8))) __bf16 bf16x8;
typedef __attribute__((ext_vector_type(4))) float fx4;

// ---------------- ws layout (bytes) ----------------
#define OFF_INPB 0            // [128][1536] bf16 = 393216
#define OFF_P2   393216       // [2][128][256] f32 = 262144

__device__ __forceinline__ fx4 mfma16(bf16x8 a, bf16x8 b, fx4 c) {
    return __builtin_amdgcn_mfma_f32_16x16x32_bf16(a, b, c, 0, 0, 0);
}

__device__ __forceinline__ bf16x8 cvt8(float4 a, float4 b) {
    bf16x8 r;
    r[0] = (__bf16)a.x; r[1] = (__bf16)a.y; r[2] = (__bf16)a.z; r[3] = (__bf16)a.w;
    r[4] = (__bf16)b.x; r[5] = (__bf16)b.y; r[6] = (__bf16)b.z; r[7] = (__bf16)b.w;
    return r;
}

// ========== kG1: inline-gather GEMM1, full K=1024 in LDS, ONE barrier ==========
// inp_bf[b][s*512+col] = emb[sample[b][s]] . t_w[col] + t_b[col] (+ p_feature)
// grid (16 n-tiles, 12 m-tiles) = 192 blocks, 256 thr (4 waves, 16x16 out each).
__global__ __launch_bounds__(256, 1)
void kG1(const int* __restrict__ sample, const int* __restrict__ gb, int n_nodes,
         const float* __restrict__ p_feature,
         const float* __restrict__ tweet_emb, const float* __restrict__ desc_emb,
         const float* __restrict__ t_w, const float* __restrict__ t_b,
         __bf16* __restrict__ inp_bf)
{
    const int n0 = blockIdx.x * 32;
    const int m0 = blockIdx.y * 32;
    const int sid = m0 >> 7;             // 0,1,2 — 32-row tiles never cross s
    const int b0  = m0 & 127;
    const int t  = threadIdx.x;
    const int wid = t >> 6, l = t & 63;
    const int mbase = (wid >> 1) * 16, nbase = (wid & 1) * 16;

    __shared__ __bf16 Alds[32 * 1024];   // 64 KB
    __shared__ __bf16 Blds[32 * 1024];   // 64 KB
    __shared__ int node_lds[32];

    // ---- u_idx scan (first node of graphs b0..b0+31), only for s != 1 ----
    if (sid != 1) {
        for (int n = t; n < n_nodes; n += 256) {
            const int g = gb[n];
            const int rel = g - b0;
            if (rel >= 0 && rel < 32) {
                if (n == 0 || gb[n - 1] != g) node_lds[rel] = n;
            }
        }
    }

    // ---- stage: 32 rows x 1024 f32 -> bf16 LDS, granule-XOR swizzled ----
    const int row = t >> 3;              // 0..31
    const int gt  = t & 7;               // granule lane within row (16 granules each)

    const int bb  = b0 + row;
    const int id  = sample[bb * 3 + sid];
    const float* erow = ((sid == 1) ? tweet_emb : desc_emb) + (size_t)id * EMB;
    const float* wrow = t_w + (size_t)(n0 + row) * EMB;

    bf16x8 areg[16], breg[16];
    #pragma unroll
    for (int j = 0; j < 16; ++j) {
        const int g = gt + j * 8;        // granule 0..127
        float4 a0 = *(const float4*)(erow + g * 8);
        float4 a1 = *(const float4*)(erow + g * 8 + 4);
        areg[j] = cvt8(a0, a1);
    }
    #pragma unroll
    for (int j = 0; j < 16; ++j) {
        const int g = gt + j * 8;
        float4 c0 = *(const float4*)(wrow + g * 8);
        float4 c1 = *(const float4*)(wrow + g * 8 + 4);
        breg[j] = cvt8(c0, c1);
    }
    #pragma unroll
    for (int j = 0; j < 16; ++j) {
        const int g  = gt + j * 8;
        const int gp = g ^ (row & 7);    // bank-quad swizzle
        *(bf16x8*)(Alds + row * 1024 + gp * 8) = areg[j];
        *(bf16x8*)(Blds + row * 1024 + gp * 8) = breg[j];
    }
    __syncthreads();

    // ---- pure ds_read + MFMA, no further barriers ----
    fx4 acc0 = {}, acc1 = {};
    const int fr = l & 15, fq = l >> 4;
    const __bf16* Ab = Alds + (mbase + fr) * 1024;
    const __bf16* Bb = Blds + (nbase + fr) * 1024;
    const int ax = (mbase + fr) & 7, bx = (nbase + fr) & 7;
    #pragma unroll
    for (int s = 0; s < 32; s += 2) {
        bf16x8 a0 = *(const bf16x8*)(Ab + ((s * 4 + fq) ^ ax) * 8);
        bf16x8 b0 = *(const bf16x8*)(Bb + ((s * 4 + fq) ^ bx) * 8);
        acc0 = mfma16(a0, b0, acc0);
        bf16x8 a1 = *(const bf16x8*)(Ab + (((s + 1) * 4 + fq) ^ ax) * 8);
        bf16x8 b1 = *(const bf16x8*)(Bb + (((s + 1) * 4 + fq) ^ bx) * 8);
        acc1 = mfma16(a1, b1, acc1);
    }

    // ---- fused epilogue ----
    const int col  = n0 + nbase + fr;
    const int roff = mbase + fq * 4;     // within-block row 0..31
    const float tb = t_b[col];
    #pragma unroll
    for (int j = 0; j < 4; ++j) {
        const int b = b0 + roff + j;
        float v = acc0[j] + acc1[j] + tb;
        if (sid != 1) {
            const int node = node_lds[roff + j] + ((sid == 2) ? 1 : 0);
            v += p_feature[(size_t)node * HID + col];
        }
        inp_bf[(size_t)b * N1 + sid * HID + col] = (__bf16)v;
    }
}

// ========== kG2: GEMM2, K=768 per half in LDS, ONE barrier, w1 inline cvt ======
// part2[ks][b][col] = inp_bf[b][ks*768:+768] . w1[col][ks*768:+768]
// grid (8 n-tiles, 4 m-tiles, 2 ks) = 64 blocks, 256 thr.
__global__ __launch_bounds__(256, 1)
void kG2(const __bf16* __restrict__ inp_bf, const float* __restrict__ w1,
         float* __restrict__ part2)
{
    const int n0 = blockIdx.x * 32;
    const int m0 = blockIdx.y * 32;
    const int ks = blockIdx.z;
    const int t  = threadIdx.x;
    const int wid = t >> 6, l = t & 63;
    const int mbase = (wid >> 1) * 16, nbase = (wid & 1) * 16;

    __shared__ __bf16 Alds[32 * 768];    // 48 KB
    __shared__ __bf16 Blds[32 * 768];    // 48 KB

    const int row = t >> 3;              // 0..31
    const int gt  = t & 7;

    bf16x8 areg[12];
    const __bf16* abase = inp_bf + (size_t)(m0 + row) * N1 + ks * 768;
    #pragma unroll
    for (int j = 0; j < 12; ++j)
        areg[j] = *(const bf16x8*)(abase + (gt + j * 8) * 8);

    float4 br[24];
    const float* bbase = w1 + (size_t)(n0 + row) * N1 + ks * 768;
    #pragma unroll
    for (int j = 0; j < 12; ++j) {
        br[2 * j]     = *(const float4*)(bbase + (gt + j * 8) * 8);
        br[2 * j + 1] = *(const float4*)(bbase + (gt + j * 8) * 8 + 4);
    }
    #pragma unroll
    for (int j = 0; j < 12; ++j) {
        const int g  = gt + j * 8;
        const int gp = g ^ (row & 7);
        *(bf16x8*)(Alds + row * 768 + gp * 8) = areg[j];
        *(bf16x8*)(Blds + row * 768 + gp * 8) = cvt8(br[2 * j], br[2 * j + 1]);
    }
    __syncthreads();

    fx4 acc0 = {}, acc1 = {};
    const int fr = l & 15, fq = l >> 4;
    const __bf16* Ab = Alds + (mbase + fr) * 768;
    const __bf16* Bb = Blds + (nbase + fr) * 768;
    const int ax = (mbase + fr) & 7, bx = (nbase + fr) & 7;
    #pragma unroll
    for (int s = 0; s < 24; s += 2) {
        bf16x8 a0 = *(const bf16x8*)(Ab + ((s * 4 + fq) ^ ax) * 8);
        bf16x8 b0 = *(const bf16x8*)(Bb + ((s * 4 + fq) ^ bx) * 8);
        acc0 = mfma16(a0, b0, acc0);
        bf16x8 a1 = *(const bf16x8*)(Ab + (((s + 1) * 4 + fq) ^ ax) * 8);
        bf16x8 b1 = *(const bf16x8*)(Bb + (((s + 1) * 4 + fq) ^ bx) * 8);
        acc1 = mfma16(a1, b1, acc1);
    }

    float* dst = part2 + (size_t)ks * P2S;
    const int col  = n0 + nbase + fr;
    const int row0 = m0 + mbase + fq * 4;
    #pragma unroll
    for (int j = 0; j < 4; ++j)
        dst[(size_t)(row0 + j) * N2 + col] = acc0[j] + acc1[j];
}

// ========== kEF: combine + redundant BN stats + affine/ReLU/dot/sigmoid ==========
// 16 blocks x 256; thread t computes column-t stats (same f32 add order as output).
__global__ __launch_bounds__(256)
void kEF(const float* __restrict__ part2, const float* __restrict__ b1,
         const float* __restrict__ gamma, const float* __restrict__ beta,
         const float* __restrict__ w2, const float* __restrict__ b2,
         float* __restrict__ out)
{
    __shared__ float s_scale[256];
    __shared__ float s_shift[256];
    const int t = threadIdx.x;

    const float bias = b1[t];
    float sum = 0.f, sq = 0.f;
    #pragma unroll 8
    for (int r = 0; r < 128; ++r) {
        float v = part2[r * N2 + t] + part2[P2S + r * N2 + t] + bias;
        sum += v;
        sq  += v * v;
    }
    const float mu  = sum * (1.0f / 128.0f);
    const float var = sq * (1.0f / 128.0f) - mu * mu;   // biased batch var
    const float rs  = rsqrtf(var + 1e-5f);
    const float sc  = gamma[t] * rs;
    s_scale[t] = sc;
    s_shift[t] = beta[t] - mu * sc;
    __syncthreads();

    const int wv = t >> 6, l = t & 63;
    #pragma unroll
    for (int rr = 0; rr < 2; ++rr) {
        const int b = blockIdx.x * 8 + wv * 2 + rr;
        float acc = 0.f;
        #pragma unroll
        for (int i = 0; i < 4; ++i) {
            const int j = l + i * 64;
            float v = part2[b * N2 + j] + part2[P2S + b * N2 + j] + b1[j];
            float x = v * s_scale[j] + s_shift[j];
            x = fmaxf(x, 0.f);
            acc += x * w2[j];
        }
        #pragma unroll
        for (int off = 32; off; off >>= 1) acc += __shfl_xor(acc, off);
        if (l == 0) out[b] = 1.0f / (1.0f + expf(-(acc + b2[0])));
    }
}

extern "C" void kernel_launch(void* const* d_in, const int* in_sizes, int n_in,
                              void* d_out, int out_size, void* d_ws, size_t ws_size,
                              hipStream_t stream) {
    const int*   sample    = (const int*)  d_in[0];
    const int*   gb        = (const int*)  d_in[1];
    const float* p_feature = (const float*)d_in[2];
    const float* tweet_emb = (const float*)d_in[3];
    const float* desc_emb  = (const float*)d_in[4];
    const float* t_w       = (const float*)d_in[5];
    const float* t_b       = (const float*)d_in[6];
    const float* w1        = (const float*)d_in[7];
    const float* b1        = (const float*)d_in[8];
    const float* gamma     = (const float*)d_in[9];
    const float* beta      = (const float*)d_in[10];
    const float* w2        = (const float*)d_in[11];
    const float* b2        = (const float*)d_in[12];
    float* out = (float*)d_out;

    char* ws = (char*)d_ws;
    __bf16* inp_bf = (__bf16*)(ws + OFF_INPB);
    float*  part2  = (float*)(ws + OFF_P2);
    const int n_nodes = in_sizes[1];

    kG1<<<dim3(16, 12), 256, 0, stream>>>(sample, gb, n_nodes, p_feature,
                                          tweet_emb, desc_emb, t_w, t_b, inp_bf);
    kG2<<<dim3(8, 4, 2), 256, 0, stream>>>(inp_bf, w1, part2);
    kEF<<<16, 256, 0, stream>>>(part2, b1, gamma, beta, w2, b2, out);
}